// Round 8
// baseline (4266.880 us; speedup 1.0000x reference)
//
#include <hip/hip_runtime.h>
#include <hip/hip_bf16.h>
#include <cstddef>
#include <cstdint>

#define NS   16384
#define HS   512
#define DS   128
#define KOBS 40
#define ES   4096
#define DTC  0.05f

typedef __bf16 bf16x8 __attribute__((ext_vector_type(8)));
typedef float  f32x4  __attribute__((ext_vector_type(4)));
typedef __hip_bfloat16 bf16_t;

__device__ __forceinline__ void async16(const void* g, void* l)
{
  __builtin_amdgcn_global_load_lds(
      (const __attribute__((address_space(1))) unsigned int*)g,
      (__attribute__((address_space(3))) unsigned int*)l, 16, 0, 0);
}

// fast tanh: 1 - 2/(1+e^{2x}); |err| ~1e-7 rel, below bf16 quantization.
__device__ __forceinline__ float fast_tanh(float x)
{
  return 1.f - 2.f / (1.f + __expf(2.f * x));
}

// ===========================================================================
// k_estep: one full Euler step  h += DT*(tanh(h@Wo1^T+bo1)@Wo2^T+bo2)
// for a 64-row strip of h. tmp lives in swizzled LDS only.
// grid 256 x 512 threads. LDS: As dbuf 2x4KB | Bs dbuf 2x32KB | tmp 64KB.
// ===========================================================================
#define LDS_AS0 0
#define LDS_AS1 4096
#define LDS_BS0 8192
#define LDS_BS1 40960
#define LDS_TMP 73728
#define LDS_EULER_TOTAL 139264

__global__ __launch_bounds__(512, 1) void k_estep(
    bf16_t* __restrict__ h,
    const bf16_t* __restrict__ Wo1, const float* __restrict__ bo1,
    const bf16_t* __restrict__ Wo2, const float* __restrict__ bo2)
{
  extern __shared__ char sm[];
  const int tid = threadIdx.x, wv = tid >> 6, lane = tid & 63;
  const int q = lane >> 4, ln = lane & 15;
  const int wc = wv * 64;                  // wave's 64-col slice of 512
  const int row0 = blockIdx.x * 64;

  // --- staging geometry ---
  // A (h strip): 64 rows x 32 k = 4KB/chunk, threads 0..255, 1 slot each
  const int srow = tid >> 2, sq = tid & 3;
  const bf16_t* gA = h + (size_t)(row0 + srow) * HS + sq * 8;
  // B: 512 cols x 32 k = 32KB/chunk, 4 slots/thread
  int bcol[4], bq[4];
#pragma unroll
  for (int i2 = 0; i2 < 4; ++i2) {
    const int s = tid + i2 * 512;
    bcol[i2] = s >> 2; bq[i2] = s & 3;
  }

  f32x4 acc[4][4];
#pragma unroll
  for (int i = 0; i < 4; ++i)
#pragma unroll
    for (int j = 0; j < 4; ++j) acc[i][j] = (f32x4){0.f, 0.f, 0.f, 0.f};

  // ---------------- GEMM1: U = tanh(h @ Wo1^T + bo1) ----------------
  {
    // prefetch chunk 0
    if (tid < 256) async16(gA, sm + LDS_AS0 + tid * 16);
#pragma unroll
    for (int i2 = 0; i2 < 4; ++i2)
      async16(Wo1 + (size_t)bcol[i2] * HS + bq[i2] * 8,
              sm + LDS_BS0 + (tid + i2 * 512) * 16);
    __syncthreads();

    for (int t = 0; t < 16; ++t) {
      if (t < 15) {
        const int nb = (t + 1) & 1;
        if (tid < 256)
          async16(gA + (t + 1) * 32, sm + (nb ? LDS_AS1 : LDS_AS0) + tid * 16);
#pragma unroll
        for (int i2 = 0; i2 < 4; ++i2)
          async16(Wo1 + (size_t)bcol[i2] * HS + (t + 1) * 32 + bq[i2] * 8,
                  sm + (nb ? LDS_BS1 : LDS_BS0) + (tid + i2 * 512) * 16);
      }
      const bf16_t* Ab = (const bf16_t*)(sm + ((t & 1) ? LDS_AS1 : LDS_AS0));
      const bf16_t* Bb = (const bf16_t*)(sm + ((t & 1) ? LDS_BS1 : LDS_BS0));
      bf16x8 a[4], b[4];
#pragma unroll
      for (int i = 0; i < 4; ++i)
        a[i] = *(const bf16x8*)(Ab + (i * 16 + ln) * 32 + q * 8);
#pragma unroll
      for (int j = 0; j < 4; ++j)
        b[j] = *(const bf16x8*)(Bb + (wc + j * 16 + ln) * 32 + q * 8);
#pragma unroll
      for (int i = 0; i < 4; ++i)
#pragma unroll
        for (int j = 0; j < 4; ++j)
          acc[i][j] = __builtin_amdgcn_mfma_f32_16x16x32_bf16(a[i], b[j], acc[i][j], 0, 0, 0);
      __syncthreads();
    }
  }

  // epilogue 1: tanh -> tmp LDS (XOR-swizzled: 16B group g at row r -> g^r)
  // also prefetch GEMM2 chunk 0 (Bs only; A comes from tmp)
#pragma unroll
  for (int i2 = 0; i2 < 4; ++i2)
    async16(Wo2 + (size_t)bcol[i2] * HS + bq[i2] * 8,
            sm + LDS_BS0 + (tid + i2 * 512) * 16);
  {
    float bj[4];
#pragma unroll
    for (int j = 0; j < 4; ++j) bj[j] = bo1[wc + j * 16 + ln];
#pragma unroll
    for (int i = 0; i < 4; ++i)
#pragma unroll
      for (int j = 0; j < 4; ++j)
#pragma unroll
        for (int r = 0; r < 4; ++r) {
          const int row = i * 16 + q * 4 + r;
          const int col = wc + j * 16 + ln;
          const int off = row * 1024 + ((((col >> 3) ^ row) & 63) << 4) + (col & 7) * 2;
          *(bf16_t*)(sm + LDS_TMP + off) =
              __float2bfloat16(fast_tanh(acc[i][j][r] + bj[j]));
        }
  }
#pragma unroll
  for (int i = 0; i < 4; ++i)
#pragma unroll
    for (int j = 0; j < 4; ++j) acc[i][j] = (f32x4){0.f, 0.f, 0.f, 0.f};
  __syncthreads();

  // ---------------- GEMM2: h += DT*(U @ Wo2^T + bo2) ----------------
  for (int t = 0; t < 16; ++t) {
    if (t < 15) {
      const int nb = (t + 1) & 1;
#pragma unroll
      for (int i2 = 0; i2 < 4; ++i2)
        async16(Wo2 + (size_t)bcol[i2] * HS + (t + 1) * 32 + bq[i2] * 8,
                sm + (nb ? LDS_BS1 : LDS_BS0) + (tid + i2 * 512) * 16);
    }
    const bf16_t* Bb = (const bf16_t*)(sm + ((t & 1) ? LDS_BS1 : LDS_BS0));
    bf16x8 a[4], b[4];
#pragma unroll
    for (int i = 0; i < 4; ++i) {
      const int row = i * 16 + ln;
      a[i] = *(const bf16x8*)(sm + LDS_TMP + row * 1024 +
                              ((((t * 4 + q) ^ row) & 63) << 4));
    }
#pragma unroll
    for (int j = 0; j < 4; ++j)
      b[j] = *(const bf16x8*)(Bb + (wc + j * 16 + ln) * 32 + q * 8);
#pragma unroll
    for (int i = 0; i < 4; ++i)
#pragma unroll
      for (int j = 0; j < 4; ++j)
        acc[i][j] = __builtin_amdgcn_mfma_f32_16x16x32_bf16(a[i], b[j], acc[i][j], 0, 0, 0);
    __syncthreads();
  }

  // epilogue 2: h RMW
  {
    float bj[4];
#pragma unroll
    for (int j = 0; j < 4; ++j) bj[j] = bo2[wc + j * 16 + ln];
#pragma unroll
    for (int i = 0; i < 4; ++i)
#pragma unroll
      for (int j = 0; j < 4; ++j)
#pragma unroll
        for (int r = 0; r < 4; ++r) {
          const int row = i * 16 + q * 4 + r;
          const int col = wc + j * 16 + ln;
          const size_t o = (size_t)(row0 + row) * HS + col;
          h[o] = __float2bfloat16(__bfloat162float(h[o]) + DTC * (acc[i][j][r] + bj[j]));
        }
  }
}

// ===========================================================================
// obs kernels — unchanged from round 7 (m97-style staged GEMM)
// ===========================================================================
template <int IT, int JT>
__device__ __forceinline__ void mfma_half(
    f32x4 (&acc)[IT][JT], const bf16_t* Ah, const bf16_t* Bh,
    int wr, int wc, int q, int ln)
{
  bf16x8 a[IT], b[JT];
#pragma unroll
  for (int i = 0; i < IT; ++i)
    a[i] = *(const bf16x8*)(Ah + (wr + i * 16 + ln) * 32 + q * 8);
#pragma unroll
  for (int j = 0; j < JT; ++j)
    b[j] = *(const bf16x8*)(Bh + (wc + j * 16 + ln) * 32 + q * 8);
#pragma unroll
  for (int i = 0; i < IT; ++i)
#pragma unroll
    for (int j = 0; j < JT; ++j)
      acc[i][j] = __builtin_amdgcn_mfma_f32_16x16x32_bf16(a[i], b[j], acc[i][j], 0, 0, 0);
}

__device__ __forceinline__ void loop128(
    f32x4 (&acc)[4][4],
    const bf16_t* __restrict__ A, int lda, const int* __restrict__ idx, int row0,
    const bf16_t* __restrict__ W, int ldw, int col0, int K,
    bf16_t* As, bf16_t* Bs)
{
  const int tid = threadIdx.x, wave = tid >> 6, lane = tid & 63;
  const int q = lane >> 4, ln = lane & 15;
  const int wr = (wave >> 1) * 64, wc = (wave & 1) * 64;
  const int srow = wave * 16 + (lane >> 2);
  const int skc  = (lane & 3) * 8;
  int ar0 = row0 + srow, ar1 = row0 + srow + 64;
  if (idx) { ar0 = idx[ar0]; ar1 = idx[ar1]; }
  const bf16_t* Ap0 = A + (size_t)ar0 * lda + skc;
  const bf16_t* Ap1 = A + (size_t)ar1 * lda + skc;
  const bf16_t* Bp0 = W + (size_t)(col0 + srow) * ldw + skc;
  const bf16_t* Bp1 = W + (size_t)(col0 + srow + 64) * ldw + skc;
  const int d0 = srow * 32 + skc, d1 = (srow + 64) * 32 + skc;

  for (int k0 = 0; k0 < K; k0 += 128) {
    __syncthreads();
#pragma unroll
    for (int s = 0; s < 4; ++s) {
      async16(Ap0 + k0 + s * 32, As + s * 4096 + d0);
      async16(Ap1 + k0 + s * 32, As + s * 4096 + d1);
      async16(Bp0 + k0 + s * 32, Bs + s * 4096 + d0);
      async16(Bp1 + k0 + s * 32, Bs + s * 4096 + d1);
    }
    __syncthreads();
#pragma unroll
    for (int s = 0; s < 4; ++s)
      mfma_half<4, 4>(acc, As + s * 4096, Bs + s * 4096, wr, wc, q, ln);
  }
}

__device__ __forceinline__ void loop64(
    f32x4 (&acc)[2][2],
    const bf16_t* __restrict__ A, int lda, int row0,
    const bf16_t* __restrict__ W, int ldw, int col0, int K,
    bf16_t* As, bf16_t* Bs)
{
  const int tid = threadIdx.x, wave = tid >> 6, lane = tid & 63;
  const int q = lane >> 4, ln = lane & 15;
  const int wr = (wave >> 1) * 32, wc = (wave & 1) * 32;
  const int srow = tid >> 2;
  const int skc  = (tid & 3) * 8;
  const bf16_t* Ap = A + (size_t)(row0 + srow) * lda + skc;
  const bf16_t* Bp = W + (size_t)(col0 + srow) * ldw + skc;
  bf16_t* As0 = As;           bf16_t* As1 = As + 64 * 32;
  bf16_t* Bs0 = Bs;           bf16_t* Bs1 = Bs + 64 * 32;
  const int d = srow * 32 + skc;

  for (int k0 = 0; k0 < K; k0 += 64) {
    __syncthreads();
    async16(Ap + k0,      As0 + d);
    async16(Bp + k0,      Bs0 + d);
    async16(Ap + k0 + 32, As1 + d);
    async16(Bp + k0 + 32, Bs1 + d);
    __syncthreads();
    mfma_half<2, 2>(acc, As0, Bs0, wr, wc, q, ln);
    mfma_half<2, 2>(acc, As1, Bs1, wr, wc, q, ln);
  }
}

// Fused: z==0 -> tmpE = relu(h[idx] @ Wp1^T + bp1)
//        z==1 -> hnewE = tanh(Xk @ Wih^T + b_ih + h[idx] @ Whh^T + b_hh)
__global__ __launch_bounds__(256) void k_obs_pre(
    const bf16_t* __restrict__ h, const int* __restrict__ idx,
    const bf16_t* __restrict__ Wp1, const float* __restrict__ bp1,
    bf16_t* __restrict__ tmpE,
    const float* __restrict__ Xk,
    const bf16_t* __restrict__ Wih, const float* __restrict__ b_ih,
    const bf16_t* __restrict__ Whh, const float* __restrict__ b_hh,
    bf16_t* __restrict__ hnewE)
{
  __shared__ bf16_t As[128 * 128], Bs[128 * 128];
  f32x4 acc[4][4] = {};
  const int tid = threadIdx.x, wave = tid >> 6, lane = tid & 63;
  const int q = lane >> 4, ln = lane & 15;
  const int wr = (wave >> 1) * 64, wc = (wave & 1) * 64;
  const int row0 = blockIdx.x * 128, col0 = blockIdx.y * 128;

  if (blockIdx.z == 0) {
    loop128(acc, h, HS, idx, row0, Wp1, HS, col0, HS, As, Bs);
#pragma unroll
    for (int j = 0; j < 4; ++j) {
      const int c = col0 + wc + j * 16 + ln;
      const float bj = bp1[c];
#pragma unroll
      for (int i = 0; i < 4; ++i)
#pragma unroll
        for (int r = 0; r < 4; ++r) {
          const int rw = row0 + wr + i * 16 + q * 4 + r;
          const float v = acc[i][j][r] + bj;
          tmpE[(size_t)rw * HS + c] = __float2bfloat16(v > 0.f ? v : 0.f);
        }
    }
  } else {
    // phase 1: Xk (fp32) @ Wih^T, K = DS = 128, single BK=128 barrier pair
    {
      const int srow = wave * 16 + (lane >> 2);
      const int skc  = (lane & 3) * 8;
      const bf16_t* Bp0 = Wih + (size_t)(col0 + srow) * DS + skc;
      const bf16_t* Bp1 = Wih + (size_t)(col0 + srow + 64) * DS + skc;
      const int d0 = srow * 32 + skc, d1 = (srow + 64) * 32 + skc;
      const int xr = tid >> 1, xh = (tid & 1) * 16;
#pragma unroll
      for (int s = 0; s < 4; ++s) {
        async16(Bp0 + s * 32, Bs + s * 4096 + d0);
        async16(Bp1 + s * 32, Bs + s * 4096 + d1);
      }
#pragma unroll
      for (int s = 0; s < 4; ++s) {
        const float* src = Xk + (size_t)(row0 + xr) * DS + s * 32 + xh;
        __attribute__((aligned(16))) bf16_t buf[16];
#pragma unroll
        for (int u = 0; u < 16; ++u) buf[u] = __float2bfloat16(src[u]);
        *(uint4*)(As + s * 4096 + xr * 32 + xh)     = *(const uint4*)buf;
        *(uint4*)(As + s * 4096 + xr * 32 + xh + 8) = *(const uint4*)(buf + 8);
      }
      __syncthreads();
#pragma unroll
      for (int s = 0; s < 4; ++s)
        mfma_half<4, 4>(acc, As + s * 4096, Bs + s * 4096, wr, wc, q, ln);
    }
    // phase 2: h[idx] @ Whh^T, K = HS
    loop128(acc, h, HS, idx, row0, Whh, HS, col0, HS, As, Bs);
#pragma unroll
    for (int j = 0; j < 4; ++j) {
      const int c = col0 + wc + j * 16 + ln;
      const float bj = b_ih[c] + b_hh[c];
#pragma unroll
      for (int i = 0; i < 4; ++i)
#pragma unroll
        for (int r = 0; r < 4; ++r) {
          const int rw = row0 + wr + i * 16 + q * 4 + r;
          hnewE[(size_t)rw * HS + c] = __float2bfloat16(fast_tanh(acc[i][j][r] + bj));
        }
    }
  }
}

// Fused: blocks [0,128) -> loss GEMM; [128,1152) -> scatter
__global__ __launch_bounds__(256) void k_obs_post(
    const bf16_t* __restrict__ tmpE, const bf16_t* __restrict__ Wp2,
    const float* __restrict__ bp2, const float* __restrict__ X,
    const float* __restrict__ Mm, float* __restrict__ accum,
    bf16_t* __restrict__ h, const bf16_t* __restrict__ hnewE,
    const int* __restrict__ idx)
{
  const int bid = blockIdx.x;
  if (bid >= 128) {
    const int t  = (bid - 128) * 256 + threadIdx.x;
    const int r  = t >> 6;
    const int c8 = (t & 63) * 8;
    const int gr = idx[r];
    *(uint4*)(h + (size_t)gr * HS + c8) = *(const uint4*)(hnewE + (size_t)r * HS + c8);
    return;
  }
  __shared__ bf16_t As[64 * 64], Bs[64 * 64];
  f32x4 acc[2][2] = {};
  const int wave = threadIdx.x >> 6, lane = threadIdx.x & 63;
  const int q = lane >> 4, ln = lane & 15;
  const int wr = (wave >> 1) * 32, wc = (wave & 1) * 32;
  const int row0 = (bid >> 1) * 64, col0 = (bid & 1) * 64;
  loop64(acc, tmpE, HS, row0, Wp2, HS, col0, HS, As, Bs);
  float ls = 0.f;
#pragma unroll
  for (int j = 0; j < 2; ++j) {
    const int c = col0 + wc + j * 16 + ln;
    const float bj = bp2[c];
#pragma unroll
    for (int i = 0; i < 2; ++i)
#pragma unroll
      for (int r = 0; r < 4; ++r) {
        const int rw = row0 + wr + i * 16 + q * 4 + r;
        const float p = acc[i][j][r] + bj;
        const size_t o = (size_t)rw * DS + c;
        ls += fabsf(X[o] - p) * Mm[o];
      }
  }
#pragma unroll
  for (int off = 32; off > 0; off >>= 1) ls += __shfl_down(ls, off);
  __shared__ float red[4];
  if (lane == 0) red[wave] = ls;
  __syncthreads();
  if (threadIdx.x == 0) atomicAdd(accum, red[0] + red[1] + red[2] + red[3]);
}

__global__ void k_cvt(const float* __restrict__ s, bf16_t* __restrict__ d, int n)
{
  const int i = blockIdx.x * 256 + threadIdx.x;
  if (i * 4 < n) {
    const float4 v = ((const float4*)s)[i];
    d[i * 4 + 0] = __float2bfloat16(v.x);
    d[i * 4 + 1] = __float2bfloat16(v.y);
    d[i * 4 + 2] = __float2bfloat16(v.z);
    d[i * 4 + 3] = __float2bfloat16(v.w);
  }
}

__global__ void k_zero(float* __restrict__ p, size_t n4)
{
  size_t i = (size_t)blockIdx.x * blockDim.x + threadIdx.x;
  const size_t st = (size_t)gridDim.x * blockDim.x;
  const float4 z = {0.f, 0.f, 0.f, 0.f};
  for (; i < n4; i += st) ((float4*)p)[i] = z;
}

__global__ void k_zero_accum(float* accum)
{
  if (threadIdx.x < 2) accum[threadIdx.x] = 0.f;
}

__global__ void k_sum(const float* __restrict__ M, size_t n4, float* __restrict__ accum)
{
  __shared__ float red[256];
  float s = 0.f;
  for (size_t i = (size_t)blockIdx.x * blockDim.x + threadIdx.x; i < n4;
       i += (size_t)gridDim.x * blockDim.x) {
    const float4 v = ((const float4*)M)[i];
    s += v.x + v.y + v.z + v.w;
  }
  red[threadIdx.x] = s;
  __syncthreads();
  for (int st = 128; st > 0; st >>= 1) {
    if (threadIdx.x < st) red[threadIdx.x] += red[threadIdx.x + st];
    __syncthreads();
  }
  if (threadIdx.x == 0) atomicAdd(accum + 1, red[0]);
}

__global__ void k_final(const float* __restrict__ accum, float* __restrict__ out)
{
  out[0] = accum[0];
  out[1] = accum[0] / accum[1];
}

// ---------------------------------------------------------------------------
extern "C" void kernel_launch(void* const* d_in, const int* in_sizes, int n_in,
                              void* d_out, int out_size, void* d_ws, size_t ws_size,
                              hipStream_t stream)
{
  const float* X    = (const float*)d_in[0];
  const float* M    = (const float*)d_in[1];
  const int*   bidx = (const int*)d_in[2];
  const float* W_ih = (const float*)d_in[3];
  const float* b_ih = (const float*)d_in[4];
  const float* W_hh = (const float*)d_in[5];
  const float* b_hh = (const float*)d_in[6];
  const float* Wo1  = (const float*)d_in[7];
  const float* bo1  = (const float*)d_in[8];
  const float* Wo2  = (const float*)d_in[9];
  const float* bo2  = (const float*)d_in[10];
  const float* Wp1  = (const float*)d_in[11];
  const float* bp1  = (const float*)d_in[12];
  const float* Wp2  = (const float*)d_in[13];
  const float* bp2  = (const float*)d_in[14];
  float* out = (float*)d_out;

  char* w = (char*)d_ws;
  bf16_t* h     = (bf16_t*)w;                         w += (size_t)NS * HS * 2;
  bf16_t* tmp   = (bf16_t*)w;                         w += (size_t)NS * HS * 2;
  bf16_t* tmpE  = (bf16_t*)w;                         w += (size_t)ES * HS * 2;
  bf16_t* hnewE = (bf16_t*)w;                         w += (size_t)ES * HS * 2;
  bf16_t* wWo1  = (bf16_t*)w;                         w += (size_t)HS * HS * 2;
  bf16_t* wWo2  = (bf16_t*)w;                         w += (size_t)HS * HS * 2;
  bf16_t* wWp1  = (bf16_t*)w;                         w += (size_t)HS * HS * 2;
  bf16_t* wWp2  = (bf16_t*)w;                         w += (size_t)DS * HS * 2;
  bf16_t* wWih  = (bf16_t*)w;                         w += (size_t)HS * DS * 2;
  bf16_t* wWhh  = (bf16_t*)w;                         w += (size_t)HS * HS * 2;
  float*  accum = (float*)w;
  (void)tmp;

  hipFuncSetAttribute((const void*)k_estep,
                      hipFuncAttributeMaxDynamicSharedMemorySize,
                      LDS_EULER_TOTAL);

  k_zero<<<2048, 256, 0, stream>>>((float*)h, (size_t)NS * HS * 2 / 16);
  k_zero_accum<<<1, 64, 0, stream>>>(accum);
  k_sum<<<2048, 256, 0, stream>>>(M, (size_t)KOBS * ES * DS / 4, accum);
  k_cvt<<<256, 256, 0, stream>>>(Wo1, wWo1, HS * HS);
  k_cvt<<<256, 256, 0, stream>>>(Wo2, wWo2, HS * HS);
  k_cvt<<<256, 256, 0, stream>>>(Wp1, wWp1, HS * HS);
  k_cvt<<<64, 256, 0, stream>>>(Wp2, wWp2, DS * HS);
  k_cvt<<<64, 256, 0, stream>>>(W_ih, wWih, HS * DS);
  k_cvt<<<256, 256, 0, stream>>>(W_hh, wWhh, HS * HS);

  const dim3 gPre(ES / 128, HS / 128, 2); // 256 blocks
  const int  gPost = 128 + ES * HS / 8 / 256;  // 128 loss + 1024 scatter

  for (int k = 0; k < KOBS; ++k) {
    const int*   idx = bidx + (size_t)k * ES;
    const float* Xk  = X + (size_t)k * ES * DS;
    const float* Mk  = M + (size_t)k * ES * DS;

    k_estep<<<NS / 64, 512, LDS_EULER_TOTAL, stream>>>(h, wWo1, bo1, wWo2, bo2);
    k_estep<<<NS / 64, 512, LDS_EULER_TOTAL, stream>>>(h, wWo1, bo1, wWo2, bo2);
    k_obs_pre <<<gPre, 256, 0, stream>>>(h, idx, wWp1, bp1, tmpE,
                                         Xk, wWih, b_ih, wWhh, b_hh, hnewE);
    k_obs_post<<<gPost, 256, 0, stream>>>(tmpE, wWp2, bp2, Xk, Mk, accum,
                                          h, hnewE, idx);
  }

  k_final<<<1, 1, 0, stream>>>(accum, out);
}

// Round 9
// 4138.831 us; speedup vs baseline: 1.0309x; 1.0309x over previous
//
#include <hip/hip_runtime.h>
#include <hip/hip_bf16.h>
#include <cstddef>
#include <cstdint>

#define NS   16384
#define HS   512
#define DS   128
#define KOBS 40
#define ES   4096
#define DTC  0.05f

typedef __bf16 bf16x8 __attribute__((ext_vector_type(8)));
typedef float  f32x4  __attribute__((ext_vector_type(4)));
typedef __hip_bfloat16 bf16_t;

__device__ __forceinline__ void async16(const void* g, void* l)
{
  __builtin_amdgcn_global_load_lds(
      (const __attribute__((address_space(1))) unsigned int*)g,
      (__attribute__((address_space(3))) unsigned int*)l, 16, 0, 0);
}

// fast tanh: 1 - 2/(1+e^{2x}); |err| ~1e-7 rel, below bf16 quantization.
__device__ __forceinline__ float fast_tanh(float x)
{
  return 1.f - 2.f / (1.f + __expf(2.f * x));
}

// ---------------------------------------------------------------------------
// One BK=32 half-step from a [rows][32] LDS tile pair (64B row stride).
// A-frag: lane holds A[m=ln][k=q*8+0..7]; C/D: col=ln, row=q*4+r.
// ---------------------------------------------------------------------------
template <int IT, int JT>
__device__ __forceinline__ void mfma_half(
    f32x4 (&acc)[IT][JT], const bf16_t* Ah, const bf16_t* Bh,
    int wr, int wc, int q, int ln)
{
  bf16x8 a[IT], b[JT];
#pragma unroll
  for (int i = 0; i < IT; ++i)
    a[i] = *(const bf16x8*)(Ah + (wr + i * 16 + ln) * 32 + q * 8);
#pragma unroll
  for (int j = 0; j < JT; ++j)
    b[j] = *(const bf16x8*)(Bh + (wc + j * 16 + ln) * 32 + q * 8);
#pragma unroll
  for (int i = 0; i < IT; ++i)
#pragma unroll
    for (int j = 0; j < JT; ++j)
      acc[i][j] = __builtin_amdgcn_mfma_f32_16x16x32_bf16(a[i], b[j], acc[i][j], 0, 0, 0);
}

// ---------------------------------------------------------------------------
// BK=128 K-loop, 128x128 block tile, 256 threads (r7-verified).
// ---------------------------------------------------------------------------
__device__ __forceinline__ void loop128(
    f32x4 (&acc)[4][4],
    const bf16_t* __restrict__ A, int lda, const int* __restrict__ idx, int row0,
    const bf16_t* __restrict__ W, int ldw, int col0, int K,
    bf16_t* As, bf16_t* Bs)
{
  const int tid = threadIdx.x, wave = tid >> 6, lane = tid & 63;
  const int q = lane >> 4, ln = lane & 15;
  const int wr = (wave >> 1) * 64, wc = (wave & 1) * 64;
  const int srow = wave * 16 + (lane >> 2);
  const int skc  = (lane & 3) * 8;
  int ar0 = row0 + srow, ar1 = row0 + srow + 64;
  if (idx) { ar0 = idx[ar0]; ar1 = idx[ar1]; }
  const bf16_t* Ap0 = A + (size_t)ar0 * lda + skc;
  const bf16_t* Ap1 = A + (size_t)ar1 * lda + skc;
  const bf16_t* Bp0 = W + (size_t)(col0 + srow) * ldw + skc;
  const bf16_t* Bp1 = W + (size_t)(col0 + srow + 64) * ldw + skc;
  const int d0 = srow * 32 + skc, d1 = (srow + 64) * 32 + skc;

  for (int k0 = 0; k0 < K; k0 += 128) {
    __syncthreads();
#pragma unroll
    for (int s = 0; s < 4; ++s) {
      async16(Ap0 + k0 + s * 32, As + s * 4096 + d0);
      async16(Ap1 + k0 + s * 32, As + s * 4096 + d1);
      async16(Bp0 + k0 + s * 32, Bs + s * 4096 + d0);
      async16(Bp1 + k0 + s * 32, Bs + s * 4096 + d1);
    }
    __syncthreads();
#pragma unroll
    for (int s = 0; s < 4; ++s)
      mfma_half<4, 4>(acc, As + s * 4096, Bs + s * 4096, wr, wc, q, ln);
  }
}

// BK=64 K-loop, 64x64 block tile, 256 threads (loss GEMM).
__device__ __forceinline__ void loop64(
    f32x4 (&acc)[2][2],
    const bf16_t* __restrict__ A, int lda, int row0,
    const bf16_t* __restrict__ W, int ldw, int col0, int K,
    bf16_t* As, bf16_t* Bs)
{
  const int tid = threadIdx.x, wave = tid >> 6, lane = tid & 63;
  const int q = lane >> 4, ln = lane & 15;
  const int wr = (wave >> 1) * 32, wc = (wave & 1) * 32;
  const int srow = tid >> 2;
  const int skc  = (tid & 3) * 8;
  const bf16_t* Ap = A + (size_t)(row0 + srow) * lda + skc;
  const bf16_t* Bp = W + (size_t)(col0 + srow) * ldw + skc;
  bf16_t* As0 = As;           bf16_t* As1 = As + 64 * 32;
  bf16_t* Bs0 = Bs;           bf16_t* Bs1 = Bs + 64 * 32;
  const int d = srow * 32 + skc;

  for (int k0 = 0; k0 < K; k0 += 64) {
    __syncthreads();
    async16(Ap + k0,      As0 + d);
    async16(Bp + k0,      Bs0 + d);
    async16(Ap + k0 + 32, As1 + d);
    async16(Bp + k0 + 32, Bs1 + d);
    __syncthreads();
    mfma_half<2, 2>(acc, As0, Bs0, wr, wc, q, ln);
    mfma_half<2, 2>(acc, As1, Bs1, wr, wc, q, ln);
  }
}

// loss body: 64x64 tile lb in [0,128): loss += sum |X - (tmpE@Wp2^T+bp2)|*M
__device__ __forceinline__ void loss_tile(
    int lb, const bf16_t* __restrict__ tmpE, const bf16_t* __restrict__ Wp2,
    const float* __restrict__ bp2, const float* __restrict__ X,
    const float* __restrict__ Mm, float* __restrict__ accum,
    bf16_t* As, bf16_t* Bs)
{
  f32x4 acc[2][2] = {};
  const int wave = threadIdx.x >> 6, lane = threadIdx.x & 63;
  const int q = lane >> 4, ln = lane & 15;
  const int wr = (wave >> 1) * 32, wc = (wave & 1) * 32;
  const int row0 = (lb >> 1) * 64, col0 = (lb & 1) * 64;
  loop64(acc, tmpE, HS, row0, Wp2, HS, col0, HS, As, Bs);
  float ls = 0.f;
#pragma unroll
  for (int j = 0; j < 2; ++j) {
    const int c = col0 + wc + j * 16 + ln;
    const float bj = bp2[c];
#pragma unroll
    for (int i = 0; i < 2; ++i)
#pragma unroll
      for (int r = 0; r < 4; ++r) {
        const int rw = row0 + wr + i * 16 + q * 4 + r;
        const float p = acc[i][j][r] + bj;
        const size_t o = (size_t)rw * DS + c;
        ls += fabsf(X[o] - p) * Mm[o];
      }
  }
#pragma unroll
  for (int off = 32; off > 0; off >>= 1) ls += __shfl_down(ls, off);
  __shared__ float red[4];
  if (lane == 0) red[wave] = ls;
  __syncthreads();
  if (threadIdx.x == 0) atomicAdd(accum, red[0] + red[1] + red[2] + red[3]);
}

// ---------------------------------------------------------------------------
// k_tanh_loss: grid (128,4) or (160,4).
//   bx <  128 : tmp = tanh(h @ Wo1^T + bo1)   (128x128 tile)
//   bx >= 128 : folded loss for PREVIOUS obs (reads tmpE_prev) — independent.
// ---------------------------------------------------------------------------
__global__ __launch_bounds__(256) void k_tanh_loss(
    const bf16_t* __restrict__ A, const bf16_t* __restrict__ W,
    const float* __restrict__ bias, bf16_t* __restrict__ out,
    const bf16_t* __restrict__ tmpE, const bf16_t* __restrict__ Wp2,
    const float* __restrict__ bp2, const float* __restrict__ X,
    const float* __restrict__ Mm, float* __restrict__ accum)
{
  __shared__ bf16_t As[128 * 128], Bs[128 * 128];
  if (blockIdx.x >= 128) {
    const int lb = (blockIdx.x - 128) * 4 + blockIdx.y;   // 0..127
    loss_tile(lb, tmpE, Wp2, bp2, X, Mm, accum, As, Bs);
    return;
  }
  f32x4 acc[4][4] = {};
  const int wave = threadIdx.x >> 6, lane = threadIdx.x & 63;
  const int q = lane >> 4, ln = lane & 15;
  const int wr = (wave >> 1) * 64, wc = (wave & 1) * 64;
  const int row0 = blockIdx.x * 128, col0 = blockIdx.y * 128;
  loop128(acc, A, HS, nullptr, row0, W, HS, col0, HS, As, Bs);
#pragma unroll
  for (int j = 0; j < 4; ++j) {
    const int c = col0 + wc + j * 16 + ln;
    const float bj = bias[c];
#pragma unroll
    for (int i = 0; i < 4; ++i)
#pragma unroll
      for (int r = 0; r < 4; ++r) {
        const int rw = row0 + wr + i * 16 + q * 4 + r;
        out[(size_t)rw * HS + c] = __float2bfloat16(fast_tanh(acc[i][j][r] + bj));
      }
  }
}

// h = h + DT * (tmp @ Wo2^T + bo2)    grid (128,4)
__global__ __launch_bounds__(256) void k_gemm_resid(
    const bf16_t* __restrict__ A, const bf16_t* __restrict__ W,
    const float* __restrict__ bias, bf16_t* __restrict__ h)
{
  __shared__ bf16_t As[128 * 128], Bs[128 * 128];
  f32x4 acc[4][4] = {};
  const int wave = threadIdx.x >> 6, lane = threadIdx.x & 63;
  const int q = lane >> 4, ln = lane & 15;
  const int wr = (wave >> 1) * 64, wc = (wave & 1) * 64;
  const int row0 = blockIdx.x * 128, col0 = blockIdx.y * 128;
  loop128(acc, A, HS, nullptr, row0, W, HS, col0, HS, As, Bs);
#pragma unroll
  for (int j = 0; j < 4; ++j) {
    const int c = col0 + wc + j * 16 + ln;
    const float bj = bias[c];
#pragma unroll
    for (int i = 0; i < 4; ++i)
#pragma unroll
      for (int r = 0; r < 4; ++r) {
        const int rw = row0 + wr + i * 16 + q * 4 + r;
        const size_t o = (size_t)rw * HS + c;
        h[o] = __float2bfloat16(__bfloat162float(h[o]) + DTC * (acc[i][j][r] + bj));
      }
  }
}

// ---------------------------------------------------------------------------
// k_obs: merged relu + rnn with SHARED gathered A-staging.
// grid (ES/64=64, HS/128=4), 256 thr, 80KB dynamic LDS.
// Per block: 64 gathered rows x 128 output cols of BOTH
//   tmpE  = relu(h[idx] @ Wp1^T + bp1)
//   hnewE = tanh(Xk @ Wih^T + b_ih + h[idx] @ Whh^T + b_hh)
// LDS: As 4x[64][32] (16KB) | Bp 4x[128][32] (32KB) | Bh 4x[128][32] (32KB)
// ---------------------------------------------------------------------------
__global__ __launch_bounds__(256) void k_obs(
    const bf16_t* __restrict__ h, const int* __restrict__ idx,
    const bf16_t* __restrict__ Wp1, const float* __restrict__ bp1,
    bf16_t* __restrict__ tmpE,
    const float* __restrict__ Xk,
    const bf16_t* __restrict__ Wih, const float* __restrict__ b_ih,
    const bf16_t* __restrict__ Whh, const float* __restrict__ b_hh,
    bf16_t* __restrict__ hnewE)
{
  extern __shared__ bf16_t sm[];
  bf16_t* As = sm;                 // 4 * 2048
  bf16_t* Bp = sm + 8192;          // 4 * 4096
  bf16_t* Bh = sm + 24576;         // 4 * 4096
  const int tid = threadIdx.x, wave = tid >> 6, lane = tid & 63;
  const int q = lane >> 4, ln = lane & 15;
  const int wr = (wave >> 1) * 32;      // row-half of 64
  const int wc = (wave & 1) * 64;       // col-half of 128
  const int row0 = blockIdx.x * 64, col0 = blockIdx.y * 128;

  // A staging geometry (gathered rows)
  const int srow = tid >> 2, skc = (tid & 3) * 8;
  const int arow = idx[row0 + srow];
  const bf16_t* gA = h + (size_t)arow * HS + skc;
  const int dA = srow * 32 + skc;
  // B staging geometry: 2 16B-units/thread/sub
  const int u0 = tid, u1 = tid + 256;
  const int br0 = u0 >> 2, be0 = (u0 & 3) * 8;
  const int br1 = u1 >> 2, be1 = (u1 & 3) * 8;

  f32x4 accR[2][4] = {}, accN[2][4] = {};

  // ---- phase X: accN += cvt(Xk) @ Wih^T  (K=128, one chunk) ----
  {
    const int xr = tid >> 2, xs = tid & 3;   // row 0..63, sub 0..3
    const float* src = Xk + (size_t)(row0 + xr) * DS + xs * 32;
    __attribute__((aligned(16))) bf16_t buf[32];
#pragma unroll
    for (int u = 0; u < 32; ++u) buf[u] = __float2bfloat16(src[u]);
#pragma unroll
    for (int v = 0; v < 4; ++v)
      *(uint4*)(As + xs * 2048 + xr * 32 + v * 8) = *(const uint4*)(buf + v * 8);
#pragma unroll
    for (int s = 0; s < 4; ++s) {
      async16(Wih + (size_t)(col0 + br0) * DS + s * 32 + be0, Bp + s * 4096 + u0 * 8);
      async16(Wih + (size_t)(col0 + br1) * DS + s * 32 + be1, Bp + s * 4096 + u1 * 8);
    }
    __syncthreads();
#pragma unroll
    for (int s = 0; s < 4; ++s)
      mfma_half<2, 4>(accN, As + s * 2048, Bp + s * 4096, wr, wc, q, ln);
  }

  // ---- main loop: K=512 over gathered h; both Wp1 and Whh per chunk ----
  for (int k0 = 0; k0 < HS; k0 += 128) {
    __syncthreads();
#pragma unroll
    for (int s = 0; s < 4; ++s) {
      async16(gA + k0 + s * 32, As + s * 2048 + dA);
      async16(Wp1 + (size_t)(col0 + br0) * HS + k0 + s * 32 + be0, Bp + s * 4096 + u0 * 8);
      async16(Wp1 + (size_t)(col0 + br1) * HS + k0 + s * 32 + be1, Bp + s * 4096 + u1 * 8);
      async16(Whh + (size_t)(col0 + br0) * HS + k0 + s * 32 + be0, Bh + s * 4096 + u0 * 8);
      async16(Whh + (size_t)(col0 + br1) * HS + k0 + s * 32 + be1, Bh + s * 4096 + u1 * 8);
    }
    __syncthreads();
#pragma unroll
    for (int s = 0; s < 4; ++s) {
      mfma_half<2, 4>(accR, As + s * 2048, Bp + s * 4096, wr, wc, q, ln);
      mfma_half<2, 4>(accN, As + s * 2048, Bh + s * 4096, wr, wc, q, ln);
    }
  }

  // ---- epilogues ----
#pragma unroll
  for (int j = 0; j < 4; ++j) {
    const int c = col0 + wc + j * 16 + ln;
    const float bR = bp1[c];
    const float bN = b_ih[c] + b_hh[c];
#pragma unroll
    for (int i = 0; i < 2; ++i)
#pragma unroll
      for (int r = 0; r < 4; ++r) {
        const int rw = row0 + wr + i * 16 + q * 4 + r;
        const float v = accR[i][j][r] + bR;
        tmpE[(size_t)rw * HS + c]  = __float2bfloat16(v > 0.f ? v : 0.f);
        hnewE[(size_t)rw * HS + c] = __float2bfloat16(fast_tanh(accN[i][j][r] + bN));
      }
  }
}

// h[idx[r], :] = hnewE[r, :]   grid 512 x 256, 32B/thread
__global__ void k_scatter(bf16_t* __restrict__ h, const bf16_t* __restrict__ src,
                          const int* __restrict__ idx)
{
  const int t  = blockIdx.x * 256 + threadIdx.x;
  const int r  = t >> 5;                 // 16 elems x 2 units per 32 threads
  const int c16 = (t & 31) * 16;
  const int gr = idx[r];
  *(uint4*)(h + (size_t)gr * HS + c16)     = *(const uint4*)(src + (size_t)r * HS + c16);
  *(uint4*)(h + (size_t)gr * HS + c16 + 8) = *(const uint4*)(src + (size_t)r * HS + c16 + 8);
}

// standalone loss (final obs), grid 128
__global__ __launch_bounds__(256) void k_loss(
    const bf16_t* __restrict__ tmpE, const bf16_t* __restrict__ Wp2,
    const float* __restrict__ bp2, const float* __restrict__ X,
    const float* __restrict__ Mm, float* __restrict__ accum)
{
  __shared__ bf16_t As[64 * 64], Bs[64 * 64];
  loss_tile(blockIdx.x, tmpE, Wp2, bp2, X, Mm, accum, As, Bs);
}

__global__ void k_cvt(const float* __restrict__ s, bf16_t* __restrict__ d, int n)
{
  const int i = blockIdx.x * 256 + threadIdx.x;
  if (i * 4 < n) {
    const float4 v = ((const float4*)s)[i];
    d[i * 4 + 0] = __float2bfloat16(v.x);
    d[i * 4 + 1] = __float2bfloat16(v.y);
    d[i * 4 + 2] = __float2bfloat16(v.z);
    d[i * 4 + 3] = __float2bfloat16(v.w);
  }
}

__global__ void k_zero(float* __restrict__ p, size_t n4)
{
  size_t i = (size_t)blockIdx.x * blockDim.x + threadIdx.x;
  const size_t st = (size_t)gridDim.x * blockDim.x;
  const float4 z = {0.f, 0.f, 0.f, 0.f};
  for (; i < n4; i += st) ((float4*)p)[i] = z;
}

__global__ void k_zero_accum(float* accum)
{
  if (threadIdx.x < 2) accum[threadIdx.x] = 0.f;
}

__global__ void k_sum(const float* __restrict__ M, size_t n4, float* __restrict__ accum)
{
  __shared__ float red[256];
  float s = 0.f;
  for (size_t i = (size_t)blockIdx.x * blockDim.x + threadIdx.x; i < n4;
       i += (size_t)gridDim.x * blockDim.x) {
    const float4 v = ((const float4*)M)[i];
    s += v.x + v.y + v.z + v.w;
  }
  red[threadIdx.x] = s;
  __syncthreads();
  for (int st = 128; st > 0; st >>= 1) {
    if (threadIdx.x < st) red[threadIdx.x] += red[threadIdx.x + st];
    __syncthreads();
  }
  if (threadIdx.x == 0) atomicAdd(accum + 1, red[0]);
}

__global__ void k_final(const float* __restrict__ accum, float* __restrict__ out)
{
  out[0] = accum[0];
  out[1] = accum[0] / accum[1];
}

// ---------------------------------------------------------------------------
extern "C" void kernel_launch(void* const* d_in, const int* in_sizes, int n_in,
                              void* d_out, int out_size, void* d_ws, size_t ws_size,
                              hipStream_t stream)
{
  const float* X    = (const float*)d_in[0];
  const float* M    = (const float*)d_in[1];
  const int*   bidx = (const int*)d_in[2];
  const float* W_ih = (const float*)d_in[3];
  const float* b_ih = (const float*)d_in[4];
  const float* W_hh = (const float*)d_in[5];
  const float* b_hh = (const float*)d_in[6];
  const float* Wo1  = (const float*)d_in[7];
  const float* bo1  = (const float*)d_in[8];
  const float* Wo2  = (const float*)d_in[9];
  const float* bo2  = (const float*)d_in[10];
  const float* Wp1  = (const float*)d_in[11];
  const float* bp1  = (const float*)d_in[12];
  const float* Wp2  = (const float*)d_in[13];
  const float* bp2  = (const float*)d_in[14];
  float* out = (float*)d_out;

  char* w = (char*)d_ws;
  bf16_t* h     = (bf16_t*)w;                         w += (size_t)NS * HS * 2;
  bf16_t* tmp   = (bf16_t*)w;                         w += (size_t)NS * HS * 2;
  bf16_t* tmpE  = (bf16_t*)w;                         w += (size_t)ES * HS * 2;
  bf16_t* hnewE = (bf16_t*)w;                         w += (size_t)ES * HS * 2;
  bf16_t* wWo1  = (bf16_t*)w;                         w += (size_t)HS * HS * 2;
  bf16_t* wWo2  = (bf16_t*)w;                         w += (size_t)HS * HS * 2;
  bf16_t* wWp1  = (bf16_t*)w;                         w += (size_t)HS * HS * 2;
  bf16_t* wWp2  = (bf16_t*)w;                         w += (size_t)DS * HS * 2;
  bf16_t* wWih  = (bf16_t*)w;                         w += (size_t)HS * DS * 2;
  bf16_t* wWhh  = (bf16_t*)w;                         w += (size_t)HS * HS * 2;
  float*  accum = (float*)w;

  const int obsLds = 40 * 1024;   // 16KB As + 32KB Bp + 32KB Bh = 80KB... (bf16 elems)
  hipFuncSetAttribute((const void*)k_obs,
                      hipFuncAttributeMaxDynamicSharedMemorySize, 81920);

  k_zero<<<2048, 256, 0, stream>>>((float*)h, (size_t)NS * HS * 2 / 16);
  k_zero_accum<<<1, 64, 0, stream>>>(accum);
  k_sum<<<2048, 256, 0, stream>>>(M, (size_t)KOBS * ES * DS / 4, accum);
  k_cvt<<<256, 256, 0, stream>>>(Wo1, wWo1, HS * HS);
  k_cvt<<<256, 256, 0, stream>>>(Wo2, wWo2, HS * HS);
  k_cvt<<<256, 256, 0, stream>>>(Wp1, wWp1, HS * HS);
  k_cvt<<<64, 256, 0, stream>>>(Wp2, wWp2, DS * HS);
  k_cvt<<<64, 256, 0, stream>>>(W_ih, wWih, HS * DS);
  k_cvt<<<256, 256, 0, stream>>>(W_hh, wWhh, HS * HS);
  (void)obsLds;

  const dim3 gE(NS / 128, HS / 128);       // (128,4)
  const dim3 gEL(NS / 128 + 32, HS / 128); // (160,4): +128 loss blocks
  const dim3 gObs(ES / 64, HS / 128);      // (64,4) = 256 blocks

  const float* Xprev = nullptr;
  const float* Mprev = nullptr;

  for (int k = 0; k < KOBS; ++k) {
    const int*   idx = bidx + (size_t)k * ES;
    const float* Xk  = X + (size_t)k * ES * DS;
    const float* Mk  = M + (size_t)k * ES * DS;

    // Euler step 1 (first tanh carries previous obs's loss blocks)
    if (k == 0)
      k_tanh_loss<<<gE, 256, 0, stream>>>(h, wWo1, bo1, tmp,
                                          nullptr, nullptr, nullptr,
                                          nullptr, nullptr, nullptr);
    else
      k_tanh_loss<<<gEL, 256, 0, stream>>>(h, wWo1, bo1, tmp,
                                           tmpE, wWp2, bp2, Xprev, Mprev, accum);
    k_gemm_resid<<<gE, 256, 0, stream>>>(tmp, wWo2, bo2, h);
    // Euler step 2
    k_tanh_loss<<<gE, 256, 0, stream>>>(h, wWo1, bo1, tmp,
                                        nullptr, nullptr, nullptr,
                                        nullptr, nullptr, nullptr);
    k_gemm_resid<<<gE, 256, 0, stream>>>(tmp, wWo2, bo2, h);

    // observation: merged relu+rnn, then scatter
    k_obs<<<gObs, 256, 81920, stream>>>(h, idx, wWp1, bp1, tmpE,
                                        Xk, wWih, b_ih, wWhh, b_hh, hnewE);
    k_scatter<<<ES * HS / 16 / 256, 256, 0, stream>>>(h, hnewE, idx);

    Xprev = Xk; Mprev = Mk;
  }

  // final obs's loss
  k_loss<<<128, 256, 0, stream>>>(tmpE, wWp2, bp2, Xprev, Mprev, accum);
  k_final<<<1, 1, 0, stream>>>(accum, out);
}

// Round 10
// 3932.685 us; speedup vs baseline: 1.0850x; 1.0524x over previous
//
#include <hip/hip_runtime.h>
#include <hip/hip_bf16.h>
#include <cstddef>
#include <cstdint>

#define NS   16384
#define HS   512
#define DS   128
#define KOBS 40
#define ES   4096
#define DTC  0.05f

typedef __bf16 bf16x8 __attribute__((ext_vector_type(8)));
typedef float  f32x4  __attribute__((ext_vector_type(4)));
typedef __hip_bfloat16 bf16_t;

__device__ __forceinline__ void async16(const void* g, void* l)
{
  __builtin_amdgcn_global_load_lds(
      (const __attribute__((address_space(1))) unsigned int*)g,
      (__attribute__((address_space(3))) unsigned int*)l, 16, 0, 0);
}

// fast tanh: 1 - 2/(1+e^{2x}); |err| ~1e-7 rel, below bf16 quantization.
__device__ __forceinline__ float fast_tanh(float x)
{
  return 1.f - 2.f / (1.f + __expf(2.f * x));
}

// ---------------------------------------------------------------------------
// One BK=32 half-step from a [rows][32] LDS tile pair (64B row stride).
// A-frag: lane holds A[m=ln][k=q*8+0..7]; C/D: col=ln, row=q*4+r.
// ---------------------------------------------------------------------------
template <int IT, int JT>
__device__ __forceinline__ void mfma_half(
    f32x4 (&acc)[IT][JT], const bf16_t* Ah, const bf16_t* Bh,
    int wr, int wc, int q, int ln)
{
  bf16x8 a[IT], b[JT];
#pragma unroll
  for (int i = 0; i < IT; ++i)
    a[i] = *(const bf16x8*)(Ah + (wr + i * 16 + ln) * 32 + q * 8);
#pragma unroll
  for (int j = 0; j < JT; ++j)
    b[j] = *(const bf16x8*)(Bh + (wc + j * 16 + ln) * 32 + q * 8);
#pragma unroll
  for (int i = 0; i < IT; ++i)
#pragma unroll
    for (int j = 0; j < JT; ++j)
      acc[i][j] = __builtin_amdgcn_mfma_f32_16x16x32_bf16(a[i], b[j], acc[i][j], 0, 0, 0);
}

// ---------------------------------------------------------------------------
// BK=128 K-loop, 128x128 block tile, 256 threads (r7-verified).
// ---------------------------------------------------------------------------
__device__ __forceinline__ void loop128(
    f32x4 (&acc)[4][4],
    const bf16_t* __restrict__ A, int lda, const int* __restrict__ idx, int row0,
    const bf16_t* __restrict__ W, int ldw, int col0, int K,
    bf16_t* As, bf16_t* Bs)
{
  const int tid = threadIdx.x, wave = tid >> 6, lane = tid & 63;
  const int q = lane >> 4, ln = lane & 15;
  const int wr = (wave >> 1) * 64, wc = (wave & 1) * 64;
  const int srow = wave * 16 + (lane >> 2);
  const int skc  = (lane & 3) * 8;
  int ar0 = row0 + srow, ar1 = row0 + srow + 64;
  if (idx) { ar0 = idx[ar0]; ar1 = idx[ar1]; }
  const bf16_t* Ap0 = A + (size_t)ar0 * lda + skc;
  const bf16_t* Ap1 = A + (size_t)ar1 * lda + skc;
  const bf16_t* Bp0 = W + (size_t)(col0 + srow) * ldw + skc;
  const bf16_t* Bp1 = W + (size_t)(col0 + srow + 64) * ldw + skc;
  const int d0 = srow * 32 + skc, d1 = (srow + 64) * 32 + skc;

  for (int k0 = 0; k0 < K; k0 += 128) {
    __syncthreads();
#pragma unroll
    for (int s = 0; s < 4; ++s) {
      async16(Ap0 + k0 + s * 32, As + s * 4096 + d0);
      async16(Ap1 + k0 + s * 32, As + s * 4096 + d1);
      async16(Bp0 + k0 + s * 32, Bs + s * 4096 + d0);
      async16(Bp1 + k0 + s * 32, Bs + s * 4096 + d1);
    }
    __syncthreads();
#pragma unroll
    for (int s = 0; s < 4; ++s)
      mfma_half<4, 4>(acc, As + s * 4096, Bs + s * 4096, wr, wc, q, ln);
  }
}

// BK=64 K-loop, 64x64 block tile, 256 threads (loss GEMM).
__device__ __forceinline__ void loop64(
    f32x4 (&acc)[2][2],
    const bf16_t* __restrict__ A, int lda, int row0,
    const bf16_t* __restrict__ W, int ldw, int col0, int K,
    bf16_t* As, bf16_t* Bs)
{
  const int tid = threadIdx.x, wave = tid >> 6, lane = tid & 63;
  const int q = lane >> 4, ln = lane & 15;
  const int wr = (wave >> 1) * 32, wc = (wave & 1) * 32;
  const int srow = tid >> 2;
  const int skc  = (tid & 3) * 8;
  const bf16_t* Ap = A + (size_t)(row0 + srow) * lda + skc;
  const bf16_t* Bp = W + (size_t)(col0 + srow) * ldw + skc;
  bf16_t* As0 = As;           bf16_t* As1 = As + 64 * 32;
  bf16_t* Bs0 = Bs;           bf16_t* Bs1 = Bs + 64 * 32;
  const int d = srow * 32 + skc;

  for (int k0 = 0; k0 < K; k0 += 64) {
    __syncthreads();
    async16(Ap + k0,      As0 + d);
    async16(Bp + k0,      Bs0 + d);
    async16(Ap + k0 + 32, As1 + d);
    async16(Bp + k0 + 32, Bs1 + d);
    __syncthreads();
    mfma_half<2, 2>(acc, As0, Bs0, wr, wc, q, ln);
    mfma_half<2, 2>(acc, As1, Bs1, wr, wc, q, ln);
  }
}

// loss body: 64x64 tile lb in [0,128): loss += sum |X - (tmpE@Wp2^T+bp2)|*M
__device__ __forceinline__ void loss_tile(
    int lb, const bf16_t* __restrict__ tmpE, const bf16_t* __restrict__ Wp2,
    const float* __restrict__ bp2, const float* __restrict__ X,
    const float* __restrict__ Mm, float* __restrict__ accum,
    bf16_t* As, bf16_t* Bs)
{
  f32x4 acc[2][2] = {};
  const int wave = threadIdx.x >> 6, lane = threadIdx.x & 63;
  const int q = lane >> 4, ln = lane & 15;
  const int wr = (wave >> 1) * 32, wc = (wave & 1) * 32;
  const int row0 = (lb >> 1) * 64, col0 = (lb & 1) * 64;
  loop64(acc, tmpE, HS, row0, Wp2, HS, col0, HS, As, Bs);
  float ls = 0.f;
#pragma unroll
  for (int j = 0; j < 2; ++j) {
    const int c = col0 + wc + j * 16 + ln;
    const float bj = bp2[c];
#pragma unroll
    for (int i = 0; i < 2; ++i)
#pragma unroll
      for (int r = 0; r < 4; ++r) {
        const int rw = row0 + wr + i * 16 + q * 4 + r;
        const float p = acc[i][j][r] + bj;
        const size_t o = (size_t)rw * DS + c;
        ls += fabsf(X[o] - p) * Mm[o];
      }
  }
#pragma unroll
  for (int off = 32; off > 0; off >>= 1) ls += __shfl_down(ls, off);
  __shared__ float red[4];
  if (lane == 0) red[wave] = ls;
  __syncthreads();
  if (threadIdx.x == 0) atomicAdd(accum, red[0] + red[1] + red[2] + red[3]);
}

// ---------------------------------------------------------------------------
// k_tanh_loss: grid (128,4) plain or (160,4) with folded loss.
//   bx <  128 : tmp = tanh(h @ Wo1^T + bo1)   (128x128 tile)
//   bx >= 128 : loss tiles for the PREVIOUS obs (reads tmpE_prev) — independent
// ---------------------------------------------------------------------------
__global__ __launch_bounds__(256) void k_tanh_loss(
    const bf16_t* __restrict__ A, const bf16_t* __restrict__ W,
    const float* __restrict__ bias, bf16_t* __restrict__ out,
    const bf16_t* __restrict__ tmpE, const bf16_t* __restrict__ Wp2,
    const float* __restrict__ bp2, const float* __restrict__ X,
    const float* __restrict__ Mm, float* __restrict__ accum)
{
  __shared__ bf16_t As[128 * 128], Bs[128 * 128];
  if (blockIdx.x >= 128) {
    const int lb = (blockIdx.x - 128) * 4 + blockIdx.y;   // 0..127
    loss_tile(lb, tmpE, Wp2, bp2, X, Mm, accum, As, Bs);
    return;
  }
  f32x4 acc[4][4] = {};
  const int wave = threadIdx.x >> 6, lane = threadIdx.x & 63;
  const int q = lane >> 4, ln = lane & 15;
  const int wr = (wave >> 1) * 64, wc = (wave & 1) * 64;
  const int row0 = blockIdx.x * 128, col0 = blockIdx.y * 128;
  loop128(acc, A, HS, nullptr, row0, W, HS, col0, HS, As, Bs);
#pragma unroll
  for (int j = 0; j < 4; ++j) {
    const int c = col0 + wc + j * 16 + ln;
    const float bj = bias[c];
#pragma unroll
    for (int i = 0; i < 4; ++i)
#pragma unroll
      for (int r = 0; r < 4; ++r) {
        const int rw = row0 + wr + i * 16 + q * 4 + r;
        out[(size_t)rw * HS + c] = __float2bfloat16(fast_tanh(acc[i][j][r] + bj));
      }
  }
}

// h = h + DT * (tmp @ Wo2^T + bo2)    grid (128,4)
__global__ __launch_bounds__(256) void k_gemm_resid(
    const bf16_t* __restrict__ A, const bf16_t* __restrict__ W,
    const float* __restrict__ bias, bf16_t* __restrict__ h)
{
  __shared__ bf16_t As[128 * 128], Bs[128 * 128];
  f32x4 acc[4][4] = {};
  const int wave = threadIdx.x >> 6, lane = threadIdx.x & 63;
  const int q = lane >> 4, ln = lane & 15;
  const int wr = (wave >> 1) * 64, wc = (wave & 1) * 64;
  const int row0 = blockIdx.x * 128, col0 = blockIdx.y * 128;
  loop128(acc, A, HS, nullptr, row0, W, HS, col0, HS, As, Bs);
#pragma unroll
  for (int j = 0; j < 4; ++j) {
    const int c = col0 + wc + j * 16 + ln;
    const float bj = bias[c];
#pragma unroll
    for (int i = 0; i < 4; ++i)
#pragma unroll
      for (int r = 0; r < 4; ++r) {
        const int rw = row0 + wr + i * 16 + q * 4 + r;
        const size_t o = (size_t)rw * HS + c;
        h[o] = __float2bfloat16(__bfloat162float(h[o]) + DTC * (acc[i][j][r] + bj));
      }
  }
}

// Fused: z==0 -> tmpE = relu(h[idx] @ Wp1^T + bp1)
//        z==1 -> hnewE = tanh(Xk @ Wih^T + b_ih + h[idx] @ Whh^T + b_hh)
// grid (ES/128, HS/128, 2)   [r7-verified]
__global__ __launch_bounds__(256) void k_obs_pre(
    const bf16_t* __restrict__ h, const int* __restrict__ idx,
    const bf16_t* __restrict__ Wp1, const float* __restrict__ bp1,
    bf16_t* __restrict__ tmpE,
    const float* __restrict__ Xk,
    const bf16_t* __restrict__ Wih, const float* __restrict__ b_ih,
    const bf16_t* __restrict__ Whh, const float* __restrict__ b_hh,
    bf16_t* __restrict__ hnewE)
{
  __shared__ bf16_t As[128 * 128], Bs[128 * 128];
  f32x4 acc[4][4] = {};
  const int tid = threadIdx.x, wave = tid >> 6, lane = tid & 63;
  const int q = lane >> 4, ln = lane & 15;
  const int wr = (wave >> 1) * 64, wc = (wave & 1) * 64;
  const int row0 = blockIdx.x * 128, col0 = blockIdx.y * 128;

  if (blockIdx.z == 0) {
    loop128(acc, h, HS, idx, row0, Wp1, HS, col0, HS, As, Bs);
#pragma unroll
    for (int j = 0; j < 4; ++j) {
      const int c = col0 + wc + j * 16 + ln;
      const float bj = bp1[c];
#pragma unroll
      for (int i = 0; i < 4; ++i)
#pragma unroll
        for (int r = 0; r < 4; ++r) {
          const int rw = row0 + wr + i * 16 + q * 4 + r;
          const float v = acc[i][j][r] + bj;
          tmpE[(size_t)rw * HS + c] = __float2bfloat16(v > 0.f ? v : 0.f);
        }
    }
  } else {
    // phase 1: Xk (fp32) @ Wih^T, K = DS = 128, single BK=128 barrier pair
    {
      const int srow = wave * 16 + (lane >> 2);
      const int skc  = (lane & 3) * 8;
      const bf16_t* Bp0 = Wih + (size_t)(col0 + srow) * DS + skc;
      const bf16_t* Bp1 = Wih + (size_t)(col0 + srow + 64) * DS + skc;
      const int d0 = srow * 32 + skc, d1 = (srow + 64) * 32 + skc;
      const int xr = tid >> 1, xh = (tid & 1) * 16;
#pragma unroll
      for (int s = 0; s < 4; ++s) {
        async16(Bp0 + s * 32, Bs + s * 4096 + d0);
        async16(Bp1 + s * 32, Bs + s * 4096 + d1);
      }
#pragma unroll
      for (int s = 0; s < 4; ++s) {
        const float* src = Xk + (size_t)(row0 + xr) * DS + s * 32 + xh;
        __attribute__((aligned(16))) bf16_t buf[16];
#pragma unroll
        for (int u = 0; u < 16; ++u) buf[u] = __float2bfloat16(src[u]);
        *(uint4*)(As + s * 4096 + xr * 32 + xh)     = *(const uint4*)buf;
        *(uint4*)(As + s * 4096 + xr * 32 + xh + 8) = *(const uint4*)(buf + 8);
      }
      __syncthreads();
#pragma unroll
      for (int s = 0; s < 4; ++s)
        mfma_half<4, 4>(acc, As + s * 4096, Bs + s * 4096, wr, wc, q, ln);
    }
    // phase 2: h[idx] @ Whh^T, K = HS
    loop128(acc, h, HS, idx, row0, Whh, HS, col0, HS, As, Bs);
#pragma unroll
    for (int j = 0; j < 4; ++j) {
      const int c = col0 + wc + j * 16 + ln;
      const float bj = b_ih[c] + b_hh[c];
#pragma unroll
      for (int i = 0; i < 4; ++i)
#pragma unroll
        for (int r = 0; r < 4; ++r) {
          const int rw = row0 + wr + i * 16 + q * 4 + r;
          hnewE[(size_t)rw * HS + c] = __float2bfloat16(fast_tanh(acc[i][j][r] + bj));
        }
    }
  }
}

// scatter-only: h[idx[r], :] = hnewE[r, :]   grid 1024 x 256, 16B/thread
__global__ void k_scatter(bf16_t* __restrict__ h, const bf16_t* __restrict__ src,
                          const int* __restrict__ idx)
{
  const int t  = blockIdx.x * 256 + threadIdx.x;
  const int r  = t >> 6;
  const int c8 = (t & 63) * 8;
  const int gr = idx[r];
  *(uint4*)(h + (size_t)gr * HS + c8) = *(const uint4*)(src + (size_t)r * HS + c8);
}

// standalone loss (final obs), grid 128
__global__ __launch_bounds__(256) void k_loss(
    const bf16_t* __restrict__ tmpE, const bf16_t* __restrict__ Wp2,
    const float* __restrict__ bp2, const float* __restrict__ X,
    const float* __restrict__ Mm, float* __restrict__ accum)
{
  __shared__ bf16_t As[64 * 64], Bs[64 * 64];
  loss_tile(blockIdx.x, tmpE, Wp2, bp2, X, Mm, accum, As, Bs);
}

__global__ void k_cvt(const float* __restrict__ s, bf16_t* __restrict__ d, int n)
{
  const int i = blockIdx.x * 256 + threadIdx.x;
  if (i * 4 < n) {
    const float4 v = ((const float4*)s)[i];
    d[i * 4 + 0] = __float2bfloat16(v.x);
    d[i * 4 + 1] = __float2bfloat16(v.y);
    d[i * 4 + 2] = __float2bfloat16(v.z);
    d[i * 4 + 3] = __float2bfloat16(v.w);
  }
}

__global__ void k_zero(float* __restrict__ p, size_t n4)
{
  size_t i = (size_t)blockIdx.x * blockDim.x + threadIdx.x;
  const size_t st = (size_t)gridDim.x * blockDim.x;
  const float4 z = {0.f, 0.f, 0.f, 0.f};
  for (; i < n4; i += st) ((float4*)p)[i] = z;
}

__global__ void k_zero_accum(float* accum)
{
  if (threadIdx.x < 2) accum[threadIdx.x] = 0.f;
}

__global__ void k_sum(const float* __restrict__ M, size_t n4, float* __restrict__ accum)
{
  __shared__ float red[256];
  float s = 0.f;
  for (size_t i = (size_t)blockIdx.x * blockDim.x + threadIdx.x; i < n4;
       i += (size_t)gridDim.x * blockDim.x) {
    const float4 v = ((const float4*)M)[i];
    s += v.x + v.y + v.z + v.w;
  }
  red[threadIdx.x] = s;
  __syncthreads();
  for (int st = 128; st > 0; st >>= 1) {
    if (threadIdx.x < st) red[threadIdx.x] += red[threadIdx.x + st];
    __syncthreads();
  }
  if (threadIdx.x == 0) atomicAdd(accum + 1, red[0]);
}

__global__ void k_final(const float* __restrict__ accum, float* __restrict__ out)
{
  out[0] = accum[0];
  out[1] = accum[0] / accum[1];
}

// ---------------------------------------------------------------------------
extern "C" void kernel_launch(void* const* d_in, const int* in_sizes, int n_in,
                              void* d_out, int out_size, void* d_ws, size_t ws_size,
                              hipStream_t stream)
{
  const float* X    = (const float*)d_in[0];
  const float* M    = (const float*)d_in[1];
  const int*   bidx = (const int*)d_in[2];
  const float* W_ih = (const float*)d_in[3];
  const float* b_ih = (const float*)d_in[4];
  const float* W_hh = (const float*)d_in[5];
  const float* b_hh = (const float*)d_in[6];
  const float* Wo1  = (const float*)d_in[7];
  const float* bo1  = (const float*)d_in[8];
  const float* Wo2  = (const float*)d_in[9];
  const float* bo2  = (const float*)d_in[10];
  const float* Wp1  = (const float*)d_in[11];
  const float* bp1  = (const float*)d_in[12];
  const float* Wp2  = (const float*)d_in[13];
  const float* bp2  = (const float*)d_in[14];
  float* out = (float*)d_out;

  char* w = (char*)d_ws;
  bf16_t* h     = (bf16_t*)w;                         w += (size_t)NS * HS * 2;
  bf16_t* tmp   = (bf16_t*)w;                         w += (size_t)NS * HS * 2;
  bf16_t* tmpE  = (bf16_t*)w;                         w += (size_t)ES * HS * 2;
  bf16_t* hnewE = (bf16_t*)w;                         w += (size_t)ES * HS * 2;
  bf16_t* wWo1  = (bf16_t*)w;                         w += (size_t)HS * HS * 2;
  bf16_t* wWo2  = (bf16_t*)w;                         w += (size_t)HS * HS * 2;
  bf16_t* wWp1  = (bf16_t*)w;                         w += (size_t)HS * HS * 2;
  bf16_t* wWp2  = (bf16_t*)w;                         w += (size_t)DS * HS * 2;
  bf16_t* wWih  = (bf16_t*)w;                         w += (size_t)HS * DS * 2;
  bf16_t* wWhh  = (bf16_t*)w;                         w += (size_t)HS * HS * 2;
  float*  accum = (float*)w;

  k_zero<<<2048, 256, 0, stream>>>((float*)h, (size_t)NS * HS * 2 / 16);
  k_zero_accum<<<1, 64, 0, stream>>>(accum);
  k_sum<<<2048, 256, 0, stream>>>(M, (size_t)KOBS * ES * DS / 4, accum);
  k_cvt<<<256, 256, 0, stream>>>(Wo1, wWo1, HS * HS);
  k_cvt<<<256, 256, 0, stream>>>(Wo2, wWo2, HS * HS);
  k_cvt<<<256, 256, 0, stream>>>(Wp1, wWp1, HS * HS);
  k_cvt<<<64, 256, 0, stream>>>(Wp2, wWp2, DS * HS);
  k_cvt<<<64, 256, 0, stream>>>(W_ih, wWih, HS * DS);
  k_cvt<<<256, 256, 0, stream>>>(W_hh, wWhh, HS * HS);

  const dim3 gE(NS / 128, HS / 128);       // (128,4) = 512 blocks
  const dim3 gEL(NS / 128 + 32, HS / 128); // (160,4): +128 folded loss blocks
  const dim3 gPre(ES / 128, HS / 128, 2);  // 256 blocks
  const int  gScat = ES * HS / 8 / 256;    // 1024 blocks

  const float* Xprev = nullptr;
  const float* Mprev = nullptr;

  for (int k = 0; k < KOBS; ++k) {
    const int*   idx = bidx + (size_t)k * ES;
    const float* Xk  = X + (size_t)k * ES * DS;
    const float* Mk  = M + (size_t)k * ES * DS;

    // Euler step 1 (first tanh of obs k carries obs k-1's loss blocks)
    if (k == 0)
      k_tanh_loss<<<gE, 256, 0, stream>>>(h, wWo1, bo1, tmp,
                                          nullptr, nullptr, nullptr,
                                          nullptr, nullptr, nullptr);
    else
      k_tanh_loss<<<gEL, 256, 0, stream>>>(h, wWo1, bo1, tmp,
                                           tmpE, wWp2, bp2, Xprev, Mprev, accum);
    k_gemm_resid<<<gE, 256, 0, stream>>>(tmp, wWo2, bo2, h);
    // Euler step 2
    k_tanh_loss<<<gE, 256, 0, stream>>>(h, wWo1, bo1, tmp,
                                        nullptr, nullptr, nullptr,
                                        nullptr, nullptr, nullptr);
    k_gemm_resid<<<gE, 256, 0, stream>>>(tmp, wWo2, bo2, h);

    // observation: fused relu+rnn (r7 structure), then scatter-only
    k_obs_pre<<<gPre, 256, 0, stream>>>(h, idx, wWp1, bp1, tmpE,
                                        Xk, wWih, b_ih, wWhh, b_hh, hnewE);
    k_scatter<<<gScat, 256, 0, stream>>>(h, hnewE, idx);

    Xprev = Xk; Mprev = Mk;
  }

  // final obs's loss
  k_loss<<<128, 256, 0, stream>>>(tmpE, wWp2, bp2, Xprev, Mprev, accum);
  k_final<<<1, 1, 0, stream>>>(accum, out);
}